// Round 20
// baseline (537.109 us; speedup 1.0000x reference)
//
#include <hip/hip_runtime.h>
#include <hip/hip_bf16.h>

#define NB 2
#define LL 2048
#define DD 512
#define HH 8
#define EE 64
#define DFF 1024
#define NL 4
#define EPS_F 1e-6f

typedef __bf16 bf16x8 __attribute__((ext_vector_type(8)));
typedef float f32x4 __attribute__((ext_vector_type(4)));

// round-to-nearest-even f32 -> bf16 bits
__device__ __forceinline__ unsigned short f2bf(float f) {
    unsigned int u = __float_as_uint(f);
    unsigned int r = (u + 0x7FFFu + ((u >> 16) & 1u)) >> 16;
    return (unsigned short)r;
}
// pack two positive f32 into bf16 pair (truncating; bias cancels in ratio)
__device__ __forceinline__ unsigned int packbf_t(float a, float b) {
    return (__float_as_uint(a) >> 16) | (__float_as_uint(b) & 0xFFFF0000u);
}
// async global->LDS, 16B per lane; LDS dest = wave base + lane*16 (linear!)
__device__ __forceinline__ void gload16(const void* g, void* l) {
    __builtin_amdgcn_global_load_lds(
        (const __attribute__((address_space(1))) unsigned int*)g,
        (__attribute__((address_space(3))) unsigned int*)l, 16, 0, 0);
}

// ---------------------------------------------------------------------------
// rope table
// ---------------------------------------------------------------------------
__global__ void rope_table_kernel(float* __restrict__ cosT, float* __restrict__ sinT) {
    int idx = blockIdx.x * 256 + threadIdx.x;
    if (idx >= LL * 32) return;
    int l = idx >> 5, i = idx & 31;
    float inv = powf(10000.f, -(float)i * (1.f / 32.f));
    float ang = (float)l * inv;
    cosT[idx] = cosf(ang);
    sinT[idx] = sinf(ang);
}

// ---------------------------------------------------------------------------
// ALL weight cast+transpose in one dispatch. 10240 blocks of 32x32 tiles.
// ---------------------------------------------------------------------------
__global__ __launch_bounds__(256) void wcast_all_kernel(const float* __restrict__ wqkv,
                                                        const float* __restrict__ wout,
                                                        const float* __restrict__ wup,
                                                        const float* __restrict__ wdown,
                                                        unsigned short* __restrict__ wt) {
    int bid = blockIdx.x;                 // 10240 = 4 layers * 2560 tiles
    int layer = bid / 2560, rem = bid % 2560;
    const float* W; unsigned short* WT; int K, N, t;
    if (rem < 768)       { W = wqkv  + (size_t)layer * 786432;  WT = wt + (size_t)layer * 786432;            K = 512;  N = 1536; t = rem; }
    else if (rem < 1024) { W = wout  + (size_t)layer * 262144;  WT = wt + 3145728 + (size_t)layer * 262144;  K = 512;  N = 512;  t = rem - 768; }
    else if (rem < 2048) { W = wup   + (size_t)layer * 1048576; WT = wt + 4194304 + (size_t)layer * 1048576; K = 512;  N = 2048; t = rem - 1024; }
    else                 { W = wdown + (size_t)layer * 524288;  WT = wt + 8388608 + (size_t)layer * 524288;  K = 1024; N = 512;  t = rem - 2048; }
    int tn = N / 32;
    int n0 = (t % tn) * 32, k0 = (t / tn) * 32;
    __shared__ float tile[32][33];
    int r = threadIdx.x >> 5, c = threadIdx.x & 31;
#pragma unroll
    for (int i = 0; i < 4; ++i)
        tile[r + 8 * i][c] = W[(size_t)(k0 + r + 8 * i) * N + n0 + c];
    __syncthreads();
#pragma unroll
    for (int i = 0; i < 4; ++i)
        WT[(size_t)(n0 + r + 8 * i) * K + k0 + c] = f2bf(tile[c][r + 8 * i]);
}

// ---------------------------------------------------------------------------
// all cond scales in ONE dispatch
// ---------------------------------------------------------------------------
__global__ __launch_bounds__(256) void cond_all_kernel(const float* __restrict__ cond,
                                                       const float* __restrict__ wn_attn,
                                                       const float* __restrict__ wn_ff,
                                                       float* __restrict__ s_all) {
    int bid = blockIdx.x;                 // 128
    int d0 = (bid & 7) * 64;
    int b = (bid >> 3) & 1;
    int which = (bid >> 4) & 1;
    int layer = bid >> 5;
    const float* W = (which ? wn_ff : wn_attn) + (size_t)layer * DD * DD;
    int t = threadIdx.x;
    int d = d0 + (t & 63), kq = t >> 6;
    const float* c = cond + b * DD + kq * 128;
    const float* Wp = W + (size_t)(kq * 128) * DD + d;
    float s = 0.f;
#pragma unroll 8
    for (int j = 0; j < 128; ++j) s = fmaf(c[j], Wp[(size_t)j * DD], s);
    __shared__ float red[4][64];
    red[kq][t & 63] = s;
    __syncthreads();
    if (t < 64) {
        float tot = 1.f + red[0][t] + red[1][t] + red[2][t] + red[3][t];
        s_all[((size_t)(layer * 2 + which) * NB + b) * DD + d0 + t] = tot;
    }
}

// ---------------------------------------------------------------------------
// RMSNorm over D=512, scale (B,D), bf16 output
// ---------------------------------------------------------------------------
__global__ __launch_bounds__(256) void rmsnorm_bf16_kernel(const float* __restrict__ x,
                                                           const float* __restrict__ scale,
                                                           unsigned short* __restrict__ y) {
    int row = blockIdx.x;
    int b = row >> 11;
    int t = threadIdx.x;
    float2 v = ((const float2*)(x + (size_t)row * DD))[t];
    float ss = v.x * v.x + v.y * v.y;
#pragma unroll
    for (int o = 32; o > 0; o >>= 1) ss += __shfl_xor(ss, o);
    __shared__ float red[4];
    if ((t & 63) == 0) red[t >> 6] = ss;
    __syncthreads();
    float tot = red[0] + red[1] + red[2] + red[3];
    float inv = rsqrtf(tot * (1.f / DD) + EPS_F);
    float2 s2 = ((const float2*)(scale + b * DD))[t];
    unsigned int lo = f2bf(v.x * s2.x * inv);
    unsigned int hi = f2bf(v.y * s2.y * inv);
    ((unsigned int*)(y + (size_t)row * DD))[t] = lo | (hi << 16);
}

// RMSNorm, scale (D,), fp32 output (final)
__global__ __launch_bounds__(256) void rmsnorm_f32_kernel(const float* __restrict__ x,
                                                          const float* __restrict__ scale,
                                                          float* __restrict__ y) {
    int row = blockIdx.x;
    int t = threadIdx.x;
    float2 v = ((const float2*)(x + (size_t)row * DD))[t];
    float ss = v.x * v.x + v.y * v.y;
#pragma unroll
    for (int o = 32; o > 0; o >>= 1) ss += __shfl_xor(ss, o);
    __shared__ float red[4];
    if ((t & 63) == 0) red[t >> 6] = ss;
    __syncthreads();
    float tot = red[0] + red[1] + red[2] + red[3];
    float inv = rsqrtf(tot * (1.f / DD) + EPS_F);
    float2 s2 = ((const float2*)scale)[t];
    float2 o2;
    o2.x = v.x * s2.x * inv;
    o2.y = v.y * s2.y * inv;
    ((float2*)(y + (size_t)row * DD))[t] = o2;
}

// ---------------------------------------------------------------------------
// bf16 MFMA GEMM, 2-phase double-buffered global_load_lds staging. BM=128.
// ---------------------------------------------------------------------------
template <int BN>
__global__ __launch_bounds__(256) void gemm_bf16_kernel(const unsigned short* __restrict__ A,
                                                        const unsigned short* __restrict__ BT,
                                                        const float* __restrict__ R,
                                                        float* __restrict__ C,
                                                        int M, int N, int K) {
    constexpr int NJ = BN / 32;           // b-frags per wave
    __shared__ __align__(16) unsigned short As[2][128 * 32];
    __shared__ __align__(16) unsigned short Bs[2][BN * 32];
    int tid = threadIdx.x;
    int n0 = blockIdx.x * BN, m0 = blockIdx.y * 128;
    int w = tid >> 6, l = tid & 63;
    int wr = w >> 1, wc = w & 1;
    int kf = 8 * (l >> 4);
    int rf = l & 15;

    auto stage = [&](int buf, int k0) {
#pragma unroll
        for (int u = 0; u < 2; ++u) {          // A: 512 chunks of 16B
            int c = u * 256 + tid;             // wave-consecutive
            int row = c >> 2, ch = c & 3;
            gload16(A + (size_t)(m0 + row) * K + k0 + ch * 8, &As[buf][c * 8]);
        }
#pragma unroll
        for (int u = 0; u < BN / 64; ++u) {    // B: BN*4 chunks
            int c = u * 256 + tid;
            int row = c >> 2, ch = c & 3;
            gload16(BT + (size_t)(n0 + row) * K + k0 + ch * 8, &Bs[buf][c * 8]);
        }
    };

    f32x4 acc[4][NJ] = {};
    const int nt = K / 32;
    stage(0, 0);
    __syncthreads();                           // buf0 ready

    for (int t = 0; t < nt; ++t) {
        if (t + 1 < nt) stage((t + 1) & 1, (t + 1) * 32);   // async prefetch
        int cur = t & 1;
        bf16x8 a[4], b[NJ];
#pragma unroll
        for (int i = 0; i < 4; ++i)
            a[i] = *(const bf16x8*)(&As[cur][(wr * 64 + i * 16 + rf) * 32 + kf]);
#pragma unroll
        for (int j = 0; j < NJ; ++j)
            b[j] = *(const bf16x8*)(&Bs[cur][(wc * (BN / 2) + j * 16 + rf) * 32 + kf]);
#pragma unroll
        for (int i = 0; i < 4; ++i)
#pragma unroll
            for (int j = 0; j < NJ; ++j)
                acc[i][j] = __builtin_amdgcn_mfma_f32_16x16x32_bf16(a[i], b[j], acc[i][j], 0, 0, 0);
        __syncthreads();                       // drain prefetch + rw fence
    }

    int rl = l >> 4, cl = l & 15;
#pragma unroll
    for (int i = 0; i < 4; ++i)
#pragma unroll
        for (int j = 0; j < NJ; ++j)
#pragma unroll
            for (int r = 0; r < 4; ++r) {
                int row = m0 + wr * 64 + i * 16 + rl * 4 + r;
                int col = n0 + wc * (BN / 2) + j * 16 + cl;
                size_t off = (size_t)row * N + col;
                float v = acc[i][j][r];
                if (R) v += R[off];
                C[off] = v;
            }
}

// ---------------------------------------------------------------------------
// bf16 MFMA GEMM, BM=64/BN=64: for N=512 GEMMs (wout/wdown) -> grid (8,64)
// = 512 blocks = 2/CU. 4 waves in 2x2, wave owns 32x32. dbuf; LDS 16KB.
// ---------------------------------------------------------------------------
__global__ __launch_bounds__(256) void gemm_bf16_64_kernel(const unsigned short* __restrict__ A,
                                                           const unsigned short* __restrict__ BT,
                                                           const float* __restrict__ R,
                                                           float* __restrict__ C,
                                                           int M, int N, int K) {
    __shared__ __align__(16) unsigned short As[2][64 * 32];
    __shared__ __align__(16) unsigned short Bs[2][64 * 32];
    int tid = threadIdx.x;
    int n0 = blockIdx.x * 64, m0 = blockIdx.y * 64;
    int w = tid >> 6, l = tid & 63;
    int wr = w >> 1, wc = w & 1;              // 2x2 wave grid, wave = 32x32
    int kf = 8 * (l >> 4);
    int rf = l & 15;

    auto stage = [&](int buf, int k0) {
        int row = tid >> 2, ch = tid & 3;      // 256 chunks each
        gload16(A + (size_t)(m0 + row) * K + k0 + ch * 8, &As[buf][tid * 8]);
        gload16(BT + (size_t)(n0 + row) * K + k0 + ch * 8, &Bs[buf][tid * 8]);
    };

    f32x4 acc[2][2] = {};
    const int nt = K / 32;
    stage(0, 0);
    __syncthreads();

    for (int t = 0; t < nt; ++t) {
        if (t + 1 < nt) stage((t + 1) & 1, (t + 1) * 32);
        int cur = t & 1;
        bf16x8 a[2], b[2];
#pragma unroll
        for (int i = 0; i < 2; ++i)
            a[i] = *(const bf16x8*)(&As[cur][(wr * 32 + i * 16 + rf) * 32 + kf]);
#pragma unroll
        for (int j = 0; j < 2; ++j)
            b[j] = *(const bf16x8*)(&Bs[cur][(wc * 32 + j * 16 + rf) * 32 + kf]);
#pragma unroll
        for (int i = 0; i < 2; ++i)
#pragma unroll
            for (int j = 0; j < 2; ++j)
                acc[i][j] = __builtin_amdgcn_mfma_f32_16x16x32_bf16(a[i], b[j], acc[i][j], 0, 0, 0);
        __syncthreads();
    }

    int rl = l >> 4, cl = l & 15;
#pragma unroll
    for (int i = 0; i < 2; ++i)
#pragma unroll
        for (int j = 0; j < 2; ++j)
#pragma unroll
            for (int r = 0; r < 4; ++r) {
                int row = m0 + wr * 32 + i * 16 + rl * 4 + r;
                int col = n0 + wc * 32 + j * 16 + cl;
                size_t off = (size_t)row * N + col;
                float v = acc[i][j][r];
                if (R) v += R[off];
                C[off] = v;
            }
}

// ---------------------------------------------------------------------------
// qkv GEMM + FUSED qknorm/rope/vtranspose epilogue. 1D grid 768, XCD-chunked
// swizzle (m-major logical order: 24 col-blocks sharing an A-tile land on
// the same XCD -> A fetched ~once per XCD instead of 8x).
// ct 0-7 q-head, 8-15 k-head, 16-23 v-head.
// ---------------------------------------------------------------------------
__global__ __launch_bounds__(256) void gemm_qkv_fused_kernel(const unsigned short* __restrict__ A,
                                                             const unsigned short* __restrict__ BT,
                                                             const float* __restrict__ qs,
                                                             const float* __restrict__ cosT,
                                                             const float* __restrict__ sinT,
                                                             unsigned short* __restrict__ qh,
                                                             unsigned short* __restrict__ kh,
                                                             unsigned short* __restrict__ vt) {
    __shared__ __align__(16) unsigned char smem[128 * 65 * sizeof(float)];  // 33280B
    unsigned short* As = (unsigned short*)smem;            // [2][128*32] = 16384B
    unsigned short* Bs = (unsigned short*)(smem + 16384);  // [2][64*32]  =  8192B
    float* ex = (float*)smem;                              // [128][65] overlay
    int tid = threadIdx.x;
    // XCD-chunked bijective swizzle: 768 = 8 * 96
    int logical = (blockIdx.x % 8) * 96 + blockIdx.x / 8;
    int ct = logical % 24, m0 = (logical / 24) * 128;      // m-major
    int n0 = ct * 64;
    int w = tid >> 6, l = tid & 63;
    int wr = w >> 1, wc = w & 1;
    int kf = 8 * (l >> 4);
    int rf = l & 15;

    auto stage = [&](int buf, int k0) {
#pragma unroll
        for (int u = 0; u < 2; ++u) {
            int c = u * 256 + tid;
            int row = c >> 2, ch = c & 3;
            gload16(A + (size_t)(m0 + row) * DD + k0 + ch * 8, &As[buf * 4096 + c * 8]);
        }
        int c = tid;                            // B: 256 chunks
        int row = c >> 2, ch = c & 3;
        gload16(BT + (size_t)(n0 + row) * DD + k0 + ch * 8, &Bs[buf * 2048 + c * 8]);
    };

    f32x4 acc[4][2] = {};
    stage(0, 0);
    __syncthreads();
    for (int t = 0; t < 16; ++t) {
        if (t + 1 < 16) stage((t + 1) & 1, (t + 1) * 32);
        int cur = t & 1;
        bf16x8 a[4], b[2];
#pragma unroll
        for (int i = 0; i < 4; ++i)
            a[i] = *(const bf16x8*)(&As[cur * 4096 + (wr * 64 + i * 16 + rf) * 32 + kf]);
#pragma unroll
        for (int j = 0; j < 2; ++j)
            b[j] = *(const bf16x8*)(&Bs[cur * 2048 + (wc * 32 + j * 16 + rf) * 32 + kf]);
#pragma unroll
        for (int i = 0; i < 4; ++i)
#pragma unroll
            for (int j = 0; j < 2; ++j)
                acc[i][j] = __builtin_amdgcn_mfma_f32_16x16x32_bf16(a[i], b[j], acc[i][j], 0, 0, 0);
        __syncthreads();
    }

    // acc -> ex (staging bufs dead; barrier above fences last reads)
    int rl = l >> 4, cl = l & 15;
#pragma unroll
    for (int i = 0; i < 4; ++i)
#pragma unroll
        for (int j = 0; j < 2; ++j)
#pragma unroll
            for (int r = 0; r < 4; ++r)
                ex[(wr * 64 + i * 16 + rl * 4 + r) * 65 + wc * 32 + j * 16 + cl] = acc[i][j][r];
    __syncthreads();

    int b = m0 >> 11;            // batch (blocks never straddle: 2048 % 128 == 0)
    int lbase = m0 & (LL - 1);
    if (ct < 16) {
        int h = ct & 7;
        bool isq = ct < 8;
        float hsc = expf(0.5f * fminf(qs[h], 4.60517019f) - 1.03972077f) * 0.35355339059f;
        if (isq) hsc *= 1.44269504f;           // fold log2(e) into q for exp2 flash
        unsigned short* dst = (isq ? qh : kh) + ((size_t)(b * HH + h) * LL) * EE;
#pragma unroll 4
        for (int it = 0; it < 32; ++it) {
            int row = w * 32 + it;
            int lloc = lbase + row;
            float v = ex[row * 65 + l];        // lane = e
            float ss = v * v;
#pragma unroll
            for (int d = 1; d < 64; d <<= 1) ss += __shfl_xor(ss, d);
            float inv = hsc * rsqrtf(ss * (1.f / EE) + EPS_F);
            float pr = ex[row * 65 + (l ^ 32)];
            int i2 = l & 31;
            float c = cosT[lloc * 32 + i2], s = sinT[lloc * 32 + i2];
            float vn = v * inv, pn = pr * inv;
            float o = (l < 32) ? (vn * c - pn * s) : (pn * s + vn * c);
            dst[(size_t)lloc * EE + l] = f2bf(o);
        }
    } else {
        int h = ct - 16;
        int bh = b * HH + h;
#pragma unroll 4
        for (int it = 0; it < 16; ++it) {
            int e = w * 16 + it;
            float v0 = ex[(2 * l) * 65 + e];
            float v1 = ex[(2 * l + 1) * 65 + e];
            unsigned int pk = (unsigned int)f2bf(v0) | ((unsigned int)f2bf(v1) << 16);
            *(unsigned int*)(vt + ((size_t)(bh * EE + e)) * LL + lbase + 2 * l) = pk;
        }
    }
}

// ---------------------------------------------------------------------------
// wup GEMM + fused geglu, 2-phase dbuf staging; f32 exchange buffer overlays
// the staging LDS (disjoint lifetime).
// ---------------------------------------------------------------------------
__global__ __launch_bounds__(256) void gemm_geglu_kernel(const unsigned short* __restrict__ A,
                                                         const unsigned short* __restrict__ BT,
                                                         unsigned short* __restrict__ G) {
    __shared__ __align__(16) unsigned char smem[128 * 65 * sizeof(float)];  // 33280B
    unsigned short* As = (unsigned short*)smem;                 // [2][128*32]
    unsigned short* Bs = (unsigned short*)(smem + 16384);       // [2][128*32]
    float* ep = (float*)smem;                                   // [128][65] overlay
    int tid = threadIdx.x;
    int n0 = blockIdx.x * 64, m0 = blockIdx.y * 128;
    int w = tid >> 6, l = tid & 63;
    int wr = w >> 1, wc = w & 1;
    int kf = 8 * (l >> 4);
    int rf = l & 15;

    auto stage = [&](int buf, int k0) {
#pragma unroll
        for (int u = 0; u < 2; ++u) {
            int c = u * 256 + tid;
            int row = c >> 2, ch = c & 3;
            gload16(A + (size_t)(m0 + row) * DD + k0 + ch * 8, &As[buf * 4096 + c * 8]);
            int grow = (row < 64) ? (n0 + row) : (DFF + n0 + row - 64);
            gload16(BT + (size_t)grow * DD + k0 + ch * 8, &Bs[buf * 4096 + c * 8]);
        }
    };

    f32x4 acc[4][4] = {};
    stage(0, 0);
    __syncthreads();

    for (int t = 0; t < 16; ++t) {
        if (t + 1 < 16) stage((t + 1) & 1, (t + 1) * 32);
        int cur = t & 1;
        bf16x8 a[4], b[4];
#pragma unroll
        for (int i = 0; i < 4; ++i)
            a[i] = *(const bf16x8*)(&As[cur * 4096 + (wr * 64 + i * 16 + rf) * 32 + kf]);
#pragma unroll
        for (int j = 0; j < 4; ++j)
            b[j] = *(const bf16x8*)(&Bs[cur * 4096 + (wc * 64 + j * 16 + rf) * 32 + kf]);
#pragma unroll
        for (int i = 0; i < 4; ++i)
#pragma unroll
            for (int j = 0; j < 4; ++j)
                acc[i][j] = __builtin_amdgcn_mfma_f32_16x16x32_bf16(a[i], b[j], acc[i][j], 0, 0, 0);
        __syncthreads();
    }

    int rl = l >> 4, cl = l & 15;
    if (wc == 0) {  // a-cols -> LDS (overlays dead staging buffers)
#pragma unroll
        for (int i = 0; i < 4; ++i)
#pragma unroll
            for (int j = 0; j < 4; ++j)
#pragma unroll
                for (int r = 0; r < 4; ++r)
                    ep[(wr * 64 + i * 16 + rl * 4 + r) * 65 + j * 16 + cl] = acc[i][j][r];
    }
    __syncthreads();
    if (wc == 1) {  // b-cols: g = a * gelu(b)
#pragma unroll
        for (int i = 0; i < 4; ++i)
#pragma unroll
            for (int j = 0; j < 4; ++j)
#pragma unroll
                for (int r = 0; r < 4; ++r) {
                    int row = wr * 64 + i * 16 + rl * 4 + r;
                    float bv = acc[i][j][r];
                    float av = ep[row * 65 + j * 16 + cl];
                    float ge = 0.5f * bv * (1.f + erff(bv * 0.70710678f));
                    G[(size_t)(m0 + row) * DFF + n0 + j * 16 + cl] = f2bf(av * ge);
                }
    }
}

// ---------------------------------------------------------------------------
// MFMA flash attention v10 + XCD-chunked swizzle: 32 consecutive logical
// blocks (same b,h,split) share the K/V panel -> co-locate on one XCD.
// 2048 = 8 * 256 exact, bijective.
// ---------------------------------------------------------------------------
#define KVB 32
#define KLDP 72
#define VLDP 40
__global__ __launch_bounds__(256) void flash_mfma_kernel(const unsigned short* __restrict__ qh,
                                                         const unsigned short* __restrict__ kh,
                                                         const unsigned short* __restrict__ vt,
                                                         unsigned short* __restrict__ op,
                                                         float* __restrict__ os) {
    __shared__ unsigned short K_lds[2][32 * KLDP];    // [buf][kv][e]
    __shared__ unsigned short VT_lds[2][64 * VLDP];   // [buf][e][kv]
    int bid = (blockIdx.x % 8) * 256 + blockIdx.x / 8;   // XCD-chunked swizzle
    int qb = bid & 31, h = (bid >> 5) & 7, b = (bid >> 8) & 1, split = bid >> 9;
    int bh = b * HH + h;
    int tid = threadIdx.x, w = tid >> 6, l = tid & 63;
    int lo = l & 15, hi4 = l >> 4;
    int q0 = qb * 64 + w * 16;

    const unsigned short* qbase = qh + ((size_t)bh * LL) * EE;
    bf16x8 qa[2];
#pragma unroll
    for (int s = 0; s < 2; ++s)
        qa[s] = *(const bf16x8*)(qbase + (size_t)(q0 + lo) * EE + s * 32 + 8 * hi4);

    // per-thread staging addresses (1 K-chunk + 1 VT-chunk of 16B each)
    int krow = tid >> 3, kch = tid & 7;      // K: 32 rows x 8 chunks
    int vrow = tid >> 2, vch = tid & 3;      // VT: 64 rows x 4 chunks
    const uint4* gK = (const uint4*)(kh + ((size_t)bh * LL + split * 16 * KVB + krow) * EE + kch * 8);
    const uint4* gV = (const uint4*)(vt + ((size_t)bh * EE + vrow) * LL + split * 16 * KVB + vch * 8);
    const int gKstep = KVB * EE / 8;         // uint4 units per tile (K)
    const int gVstep = KVB / 8;              // uint4 units per tile (VT)
    unsigned short* ldsK = &K_lds[0][krow * KLDP + kch * 8];
    unsigned short* ldsV = &VT_lds[0][vrow * VLDP + vch * 8];
    const int ldsKsz = 32 * KLDP, ldsVsz = 64 * VLDP;

    uint4 pk = *gK, pv = *gV;
    *(uint4*)ldsK = pk;
    *(uint4*)ldsV = pv;
    __syncthreads();

    f32x4 oacc[4] = {};
    float rsum = 0.f;
    const bool lowg = hi4 < 2;               // g in {0,1}
    const bool oddg = hi4 & 1;
    const bool topg = hi4 >> 1;
    const int par = (hi4 ^ (hi4 >> 1)) & 1;  // 0 for g0,g3; 1 for g1,g2

    for (int t = 0; t < 16; ++t) {
        int cur = t & 1;
        if (t + 1 < 16) {                    // early issue: latency hides under compute
            pk = gK[(t + 1) * gKstep];
            pv = gV[(t + 1) * gVstep];
        }

        // S^T = K Q^T (swapped): thread holds S[kv = 16nf + 4*hi4 + r][q = lo]
        const unsigned short* Kc = &K_lds[cur][0];
        const unsigned short* Vc = &VT_lds[cur][0];
        f32x4 S[2] = {};
        __builtin_amdgcn_s_setprio(1);
#pragma unroll
        for (int nf = 0; nf < 2; ++nf)
#pragma unroll
            for (int s = 0; s < 2; ++s) {
                bf16x8 kb = *(const bf16x8*)&Kc[(nf * 16 + lo) * KLDP + s * 32 + 8 * hi4];
                S[nf] = __builtin_amdgcn_mfma_f32_16x16x32_bf16(kb, qa[s], S[nf], 0, 0, 0);
            }
        __builtin_amdgcn_s_setprio(0);

        // p = exp2(S) (log2e pre-folded into q)
        float p0 = exp2f(S[0][0]), p1 = exp2f(S[0][1]), p2 = exp2f(S[0][2]), p3 = exp2f(S[0][3]);
        float p4 = exp2f(S[1][0]), p5 = exp2f(S[1][1]), p6 = exp2f(S[1][2]), p7 = exp2f(S[1][3]);

        // row(q=lo) sum across the 4 lanes sharing lo
        float ts = ((p0 + p1) + (p2 + p3)) + ((p4 + p5) + (p6 + p7));
        ts += __shfl_xor(ts, 16);
        ts += __shfl_xor(ts, 32);
        rsum += ts;

        // pack kv-pairs: u0,u1 = pairs {2g,2g+1}; u2,u3 = {8+2g,8+2g+1}
        unsigned int u0 = packbf_t(p0, p1), u1 = packbf_t(p2, p3);
        unsigned int u2 = packbf_t(p4, p5), u3 = packbf_t(p6, p7);
        // butterfly: lane g ends with pairs {4g..4g+3} = A-fragment for q=lo
        unsigned int keep0 = lowg ? u0 : u2, keep1 = lowg ? u1 : u3;
        unsigned int sA0 = lowg ? u2 : u0, sA1 = lowg ? u3 : u1;
        unsigned int rA0 = __shfl_xor(sA0, 32), rA1 = __shfl_xor(sA1, 32);
        unsigned int sB0 = par ? keep0 : rA0, sB1 = par ? keep1 : rA1;
        unsigned int rB0 = __shfl_xor(sB0, 16), rB1 = __shfl_xor(sB1, 16);
        uint4 paw;
        paw.x = oddg ? rB0 : (topg ? rA0 : keep0);
        paw.y = oddg ? rB1 : (topg ? rA1 : keep1);
        paw.z = oddg ? (topg ? keep0 : rA0) : rB0;
        paw.w = oddg ? (topg ? keep1 : rA1) : rB1;
        bf16x8 pa = *(bf16x8*)&paw;

        // O += P V
        __builtin_amdgcn_s_setprio(1);
#pragma unroll
        for (int nf = 0; nf < 4; ++nf) {
            bf16x8 vb = *(const bf16x8*)&Vc[(nf * 16 + lo) * VLDP + 8 * hi4];
            oacc[nf] = __builtin_amdgcn_mfma_f32_16x16x32_bf16(pa, vb, oacc[nf], 0, 0, 0);
        }
        __builtin_amdgcn_s_setprio(0);

        // write prefetched tile into the other buffer (its readers finished
        // before the PREVIOUS barrier), then one barrier.
        if (t + 1 < 16) {
            *(uint4*)(ldsK + (cur ^ 1) * ldsKsz) = pk;
            *(uint4*)(ldsV + (cur ^ 1) * ldsVsz) = pv;
        }
        __syncthreads();
    }

    unsigned short* opp = op + (size_t)split * (NB * LL * DD);
#pragma unroll
    for (int r = 0; r < 4; ++r) {
        int row = q0 + hi4 * 4 + r;
        unsigned short* optr = opp + ((size_t)(b * LL + row)) * DD + h * EE;
#pragma unroll
        for (int nf = 0; nf < 4; ++nf)
            optr[nf * 16 + lo] = f2bf(oacc[nf][r]);    // RNE partials
    }
    if (hi4 == 0)
        os[split * (NB * HH * LL) + bh * LL + q0 + lo] = rsum;
}

// ---------------------------------------------------------------------------
// combine 4 bf16 partials: oh = bf16( sum_sp op[sp] / sum_sp s[sp] )
// ---------------------------------------------------------------------------
__global__ __launch_bounds__(256) void attn_combine_kernel(const unsigned short* __restrict__ op,
                                                           const float* __restrict__ os,
                                                           unsigned short* __restrict__ oh) {
    int idx = (blockIdx.x * 256 + threadIdx.x) * 8;   // over 2M elems
    int col = idx & 511;
    int h = col >> 6;
    int row = (idx >> 9) & (LL - 1);
    int b = idx >> 20;
    int bh = b * HH + h;
    float s = 0.f;
    float a[8] = {};
#pragma unroll
    for (int sp = 0; sp < 4; ++sp) {
        s += os[sp * (NB * HH * LL) + bh * LL + row];
        uint4 t = *(const uint4*)(op + (size_t)sp * (NB * LL * DD) + idx);
        unsigned int dw[4] = {t.x, t.y, t.z, t.w};
#pragma unroll
        for (int j = 0; j < 4; ++j) {
            a[2 * j]     += __uint_as_float(dw[j] << 16);
            a[2 * j + 1] += __uint_as_float(dw[j] & 0xFFFF0000u);
        }
    }
    float inv = 1.f / s;
    uint4 o4;
    unsigned int* po = (unsigned int*)&o4;
#pragma unroll
    for (int j = 0; j < 4; ++j)
        po[j] = (unsigned int)f2bf(a[2 * j] * inv) | ((unsigned int)f2bf(a[2 * j + 1] * inv) << 16);
    *(uint4*)(oh + idx) = o4;
}

// ---------------------------------------------------------------------------
extern "C" void kernel_launch(void* const* d_in, const int* in_sizes, int n_in,
                              void* d_out, int out_size, void* d_ws, size_t ws_size,
                              hipStream_t stream) {
    const float* x        = (const float*)d_in[0];
    const float* cond     = (const float*)d_in[1];
    // d_in[2] attn_mask: bias varies only with query index -> softmax-invariant -> unused
    const float* wn_attn  = (const float*)d_in[3];
    const float* wqkv     = (const float*)d_in[4];
    const float* qk_scale = (const float*)d_in[5];
    const float* wout     = (const float*)d_in[6];
    const float* wn_ff    = (const float*)d_in[7];
    const float* wup      = (const float*)d_in[8];
    const float* wdown    = (const float*)d_in[9];
    const float* out_scale= (const float*)d_in[10];
    float* out = (float*)d_out;

    const int TOK = NB * LL;                 // 4096
    const size_t nHx = (size_t)TOK * DD;     // 2,097,152
    const size_t M = 1024 * 1024;

    float* ws = (float*)d_ws;
    float* hx  = ws;                                   // [0, 2M) f32
    unsigned short* y_bf = (unsigned short*)(ws + 2 * M);      // [2M,3M)
    unsigned short* op   = (unsigned short*)(ws + 3 * M);      // [3M,7M): 4 splits x 2M ushort
    unsigned short* qh_bf = (unsigned short*)(ws + 11 * M);    // [11M,12M)
    unsigned short* g_bf  = (unsigned short*)(ws + 11 * M);    // [11M,13M) (qh/kh dead by geglu)
    unsigned short* kh_bf = (unsigned short*)(ws + 12 * M);    // [12M,13M)
    unsigned short* vt_bf = (unsigned short*)(ws + 13 * M);    // [13M,14M)
    unsigned short* oh_bf = (unsigned short*)(ws + 14 * M);    // [14M,15M)
    unsigned short* wt = (unsigned short*)(ws + 15 * M);       // [15M,20M)
    float* smal  = ws + 20 * M;
    float* s_all = smal;                      // 8192
    float* os    = smal + 8192;               // 4 x 32768 = 131072
    float* cosT  = os + 131072;
    float* sinT  = cosT + 65536;

    hipMemcpyAsync(hx, x, nHx * sizeof(float), hipMemcpyDeviceToDevice, stream);
    rope_table_kernel<<<256, 256, 0, stream>>>(cosT, sinT);
    cond_all_kernel<<<128, 256, 0, stream>>>(cond, wn_attn, wn_ff, s_all);
    wcast_all_kernel<<<10240, 256, 0, stream>>>(wqkv, wout, wup, wdown, wt);

    unsigned short* wqkvT  = wt;
    unsigned short* woutT  = wt + 3145728;
    unsigned short* wupT   = wt + 4194304;
    unsigned short* wdownT = wt + 8388608;

    for (int layer = 0; layer < NL; ++layer) {
        const float* qs = qk_scale + layer * HH;

        rmsnorm_bf16_kernel<<<TOK, 256, 0, stream>>>(hx, s_all + (size_t)(layer * 2 + 0) * NB * DD, y_bf);
        gemm_qkv_fused_kernel<<<768, 256, 0, stream>>>(
            y_bf, wqkvT + (size_t)layer * 786432, qs, cosT, sinT, qh_bf, kh_bf, vt_bf);
        flash_mfma_kernel<<<2048, 256, 0, stream>>>(qh_bf, kh_bf, vt_bf, op, os);
        attn_combine_kernel<<<1024, 256, 0, stream>>>(op, os, oh_bf);
        gemm_bf16_64_kernel<<<dim3(512 / 64, TOK / 64), 256, 0, stream>>>(
            oh_bf, woutT + (size_t)layer * 262144, hx, hx, TOK, 512, 512);

        rmsnorm_bf16_kernel<<<TOK, 256, 0, stream>>>(hx, s_all + (size_t)(layer * 2 + 1) * NB * DD, y_bf);
        gemm_geglu_kernel<<<dim3(16, 32), 256, 0, stream>>>(
            y_bf, wupT + (size_t)layer * 1048576, g_bf);
        gemm_bf16_64_kernel<<<dim3(512 / 64, TOK / 64), 256, 0, stream>>>(
            g_bf, wdownT + (size_t)layer * 524288, hx, hx, TOK, 512, 1024);
    }
    rmsnorm_f32_kernel<<<TOK, 256, 0, stream>>>(hx, out_scale, out);
}

// Round 21
// 525.706 us; speedup vs baseline: 1.0217x; 1.0217x over previous
//
#include <hip/hip_runtime.h>
#include <hip/hip_bf16.h>

#define NB 2
#define LL 2048
#define DD 512
#define HH 8
#define EE 64
#define DFF 1024
#define NL 4
#define EPS_F 1e-6f

typedef __bf16 bf16x8 __attribute__((ext_vector_type(8)));
typedef float f32x4 __attribute__((ext_vector_type(4)));

// round-to-nearest-even f32 -> bf16 bits
__device__ __forceinline__ unsigned short f2bf(float f) {
    unsigned int u = __float_as_uint(f);
    unsigned int r = (u + 0x7FFFu + ((u >> 16) & 1u)) >> 16;
    return (unsigned short)r;
}
// pack two positive f32 into bf16 pair (truncating; bias cancels in ratio)
__device__ __forceinline__ unsigned int packbf_t(float a, float b) {
    return (__float_as_uint(a) >> 16) | (__float_as_uint(b) & 0xFFFF0000u);
}
// async global->LDS, 16B per lane; LDS dest = wave base + lane*16 (linear!)
__device__ __forceinline__ void gload16(const void* g, void* l) {
    __builtin_amdgcn_global_load_lds(
        (const __attribute__((address_space(1))) unsigned int*)g,
        (__attribute__((address_space(3))) unsigned int*)l, 16, 0, 0);
}

// ---------------------------------------------------------------------------
// rope table
// ---------------------------------------------------------------------------
__global__ void rope_table_kernel(float* __restrict__ cosT, float* __restrict__ sinT) {
    int idx = blockIdx.x * 256 + threadIdx.x;
    if (idx >= LL * 32) return;
    int l = idx >> 5, i = idx & 31;
    float inv = powf(10000.f, -(float)i * (1.f / 32.f));
    float ang = (float)l * inv;
    cosT[idx] = cosf(ang);
    sinT[idx] = sinf(ang);
}

// ---------------------------------------------------------------------------
// ALL weight cast+transpose in one dispatch. 10240 blocks of 32x32 tiles.
// ---------------------------------------------------------------------------
__global__ __launch_bounds__(256) void wcast_all_kernel(const float* __restrict__ wqkv,
                                                        const float* __restrict__ wout,
                                                        const float* __restrict__ wup,
                                                        const float* __restrict__ wdown,
                                                        unsigned short* __restrict__ wt) {
    int bid = blockIdx.x;                 // 10240 = 4 layers * 2560 tiles
    int layer = bid / 2560, rem = bid % 2560;
    const float* W; unsigned short* WT; int K, N, t;
    if (rem < 768)       { W = wqkv  + (size_t)layer * 786432;  WT = wt + (size_t)layer * 786432;            K = 512;  N = 1536; t = rem; }
    else if (rem < 1024) { W = wout  + (size_t)layer * 262144;  WT = wt + 3145728 + (size_t)layer * 262144;  K = 512;  N = 512;  t = rem - 768; }
    else if (rem < 2048) { W = wup   + (size_t)layer * 1048576; WT = wt + 4194304 + (size_t)layer * 1048576; K = 512;  N = 2048; t = rem - 1024; }
    else                 { W = wdown + (size_t)layer * 524288;  WT = wt + 8388608 + (size_t)layer * 524288;  K = 1024; N = 512;  t = rem - 2048; }
    int tn = N / 32;
    int n0 = (t % tn) * 32, k0 = (t / tn) * 32;
    __shared__ float tile[32][33];
    int r = threadIdx.x >> 5, c = threadIdx.x & 31;
#pragma unroll
    for (int i = 0; i < 4; ++i)
        tile[r + 8 * i][c] = W[(size_t)(k0 + r + 8 * i) * N + n0 + c];
    __syncthreads();
#pragma unroll
    for (int i = 0; i < 4; ++i)
        WT[(size_t)(n0 + r + 8 * i) * K + k0 + c] = f2bf(tile[c][r + 8 * i]);
}

// ---------------------------------------------------------------------------
// all cond scales in ONE dispatch
// ---------------------------------------------------------------------------
__global__ __launch_bounds__(256) void cond_all_kernel(const float* __restrict__ cond,
                                                       const float* __restrict__ wn_attn,
                                                       const float* __restrict__ wn_ff,
                                                       float* __restrict__ s_all) {
    int bid = blockIdx.x;                 // 128
    int d0 = (bid & 7) * 64;
    int b = (bid >> 3) & 1;
    int which = (bid >> 4) & 1;
    int layer = bid >> 5;
    const float* W = (which ? wn_ff : wn_attn) + (size_t)layer * DD * DD;
    int t = threadIdx.x;
    int d = d0 + (t & 63), kq = t >> 6;
    const float* c = cond + b * DD + kq * 128;
    const float* Wp = W + (size_t)(kq * 128) * DD + d;
    float s = 0.f;
#pragma unroll 8
    for (int j = 0; j < 128; ++j) s = fmaf(c[j], Wp[(size_t)j * DD], s);
    __shared__ float red[4][64];
    red[kq][t & 63] = s;
    __syncthreads();
    if (t < 64) {
        float tot = 1.f + red[0][t] + red[1][t] + red[2][t] + red[3][t];
        s_all[((size_t)(layer * 2 + which) * NB + b) * DD + d0 + t] = tot;
    }
}

// ---------------------------------------------------------------------------
// RMSNorm over D=512, scale (B,D), bf16 output
// ---------------------------------------------------------------------------
__global__ __launch_bounds__(256) void rmsnorm_bf16_kernel(const float* __restrict__ x,
                                                           const float* __restrict__ scale,
                                                           unsigned short* __restrict__ y) {
    int row = blockIdx.x;
    int b = row >> 11;
    int t = threadIdx.x;
    float2 v = ((const float2*)(x + (size_t)row * DD))[t];
    float ss = v.x * v.x + v.y * v.y;
#pragma unroll
    for (int o = 32; o > 0; o >>= 1) ss += __shfl_xor(ss, o);
    __shared__ float red[4];
    if ((t & 63) == 0) red[t >> 6] = ss;
    __syncthreads();
    float tot = red[0] + red[1] + red[2] + red[3];
    float inv = rsqrtf(tot * (1.f / DD) + EPS_F);
    float2 s2 = ((const float2*)(scale + b * DD))[t];
    unsigned int lo = f2bf(v.x * s2.x * inv);
    unsigned int hi = f2bf(v.y * s2.y * inv);
    ((unsigned int*)(y + (size_t)row * DD))[t] = lo | (hi << 16);
}

// RMSNorm, scale (D,), fp32 output (final)
__global__ __launch_bounds__(256) void rmsnorm_f32_kernel(const float* __restrict__ x,
                                                          const float* __restrict__ scale,
                                                          float* __restrict__ y) {
    int row = blockIdx.x;
    int t = threadIdx.x;
    float2 v = ((const float2*)(x + (size_t)row * DD))[t];
    float ss = v.x * v.x + v.y * v.y;
#pragma unroll
    for (int o = 32; o > 0; o >>= 1) ss += __shfl_xor(ss, o);
    __shared__ float red[4];
    if ((t & 63) == 0) red[t >> 6] = ss;
    __syncthreads();
    float tot = red[0] + red[1] + red[2] + red[3];
    float inv = rsqrtf(tot * (1.f / DD) + EPS_F);
    float2 s2 = ((const float2*)scale)[t];
    float2 o2;
    o2.x = v.x * s2.x * inv;
    o2.y = v.y * s2.y * inv;
    ((float2*)(y + (size_t)row * DD))[t] = o2;
}

// ---------------------------------------------------------------------------
// bf16 MFMA GEMM, 2-phase double-buffered global_load_lds staging. BM=128.
// ---------------------------------------------------------------------------
template <int BN>
__global__ __launch_bounds__(256) void gemm_bf16_kernel(const unsigned short* __restrict__ A,
                                                        const unsigned short* __restrict__ BT,
                                                        const float* __restrict__ R,
                                                        float* __restrict__ C,
                                                        int M, int N, int K) {
    constexpr int NJ = BN / 32;           // b-frags per wave
    __shared__ __align__(16) unsigned short As[2][128 * 32];
    __shared__ __align__(16) unsigned short Bs[2][BN * 32];
    int tid = threadIdx.x;
    int n0 = blockIdx.x * BN, m0 = blockIdx.y * 128;
    int w = tid >> 6, l = tid & 63;
    int wr = w >> 1, wc = w & 1;
    int kf = 8 * (l >> 4);
    int rf = l & 15;

    auto stage = [&](int buf, int k0) {
#pragma unroll
        for (int u = 0; u < 2; ++u) {          // A: 512 chunks of 16B
            int c = u * 256 + tid;             // wave-consecutive
            int row = c >> 2, ch = c & 3;
            gload16(A + (size_t)(m0 + row) * K + k0 + ch * 8, &As[buf][c * 8]);
        }
#pragma unroll
        for (int u = 0; u < BN / 64; ++u) {    // B: BN*4 chunks
            int c = u * 256 + tid;
            int row = c >> 2, ch = c & 3;
            gload16(BT + (size_t)(n0 + row) * K + k0 + ch * 8, &Bs[buf][c * 8]);
        }
    };

    f32x4 acc[4][NJ] = {};
    const int nt = K / 32;
    stage(0, 0);
    __syncthreads();                           // buf0 ready

    for (int t = 0; t < nt; ++t) {
        if (t + 1 < nt) stage((t + 1) & 1, (t + 1) * 32);   // async prefetch
        int cur = t & 1;
        bf16x8 a[4], b[NJ];
#pragma unroll
        for (int i = 0; i < 4; ++i)
            a[i] = *(const bf16x8*)(&As[cur][(wr * 64 + i * 16 + rf) * 32 + kf]);
#pragma unroll
        for (int j = 0; j < NJ; ++j)
            b[j] = *(const bf16x8*)(&Bs[cur][(wc * (BN / 2) + j * 16 + rf) * 32 + kf]);
#pragma unroll
        for (int i = 0; i < 4; ++i)
#pragma unroll
            for (int j = 0; j < NJ; ++j)
                acc[i][j] = __builtin_amdgcn_mfma_f32_16x16x32_bf16(a[i], b[j], acc[i][j], 0, 0, 0);
        __syncthreads();                       // drain prefetch + rw fence
    }

    int rl = l >> 4, cl = l & 15;
#pragma unroll
    for (int i = 0; i < 4; ++i)
#pragma unroll
        for (int j = 0; j < NJ; ++j)
#pragma unroll
            for (int r = 0; r < 4; ++r) {
                int row = m0 + wr * 64 + i * 16 + rl * 4 + r;
                int col = n0 + wc * (BN / 2) + j * 16 + cl;
                size_t off = (size_t)row * N + col;
                float v = acc[i][j][r];
                if (R) v += R[off];
                C[off] = v;
            }
}

// ---------------------------------------------------------------------------
// bf16 MFMA GEMM, BM=64/BN=64 for N=512 GEMMs. 1D grid 512 = 8*64 with
// XCD-chunked swizzle: chunk = 8 m-panels x all 8 n-blocks -> A panel + whole
// B fetched ~once per XCD. 4 waves in 2x2, wave owns 32x32. dbuf; LDS 16KB.
// ---------------------------------------------------------------------------
__global__ __launch_bounds__(256) void gemm_bf16_64_kernel(const unsigned short* __restrict__ A,
                                                           const unsigned short* __restrict__ BT,
                                                           const float* __restrict__ R,
                                                           float* __restrict__ C,
                                                           int M, int N, int K) {
    __shared__ __align__(16) unsigned short As[2][64 * 32];
    __shared__ __align__(16) unsigned short Bs[2][64 * 32];
    int tid = threadIdx.x;
    int logical = (blockIdx.x % 8) * 64 + blockIdx.x / 8;   // 512 = 8*64 bijective
    int n0 = (logical & 7) * 64, m0 = (logical >> 3) * 64;
    int w = tid >> 6, l = tid & 63;
    int wr = w >> 1, wc = w & 1;              // 2x2 wave grid, wave = 32x32
    int kf = 8 * (l >> 4);
    int rf = l & 15;

    auto stage = [&](int buf, int k0) {
        int row = tid >> 2, ch = tid & 3;      // 256 chunks each
        gload16(A + (size_t)(m0 + row) * K + k0 + ch * 8, &As[buf][tid * 8]);
        gload16(BT + (size_t)(n0 + row) * K + k0 + ch * 8, &Bs[buf][tid * 8]);
    };

    f32x4 acc[2][2] = {};
    const int nt = K / 32;
    stage(0, 0);
    __syncthreads();

    for (int t = 0; t < nt; ++t) {
        if (t + 1 < nt) stage((t + 1) & 1, (t + 1) * 32);
        int cur = t & 1;
        bf16x8 a[2], b[2];
#pragma unroll
        for (int i = 0; i < 2; ++i)
            a[i] = *(const bf16x8*)(&As[cur][(wr * 32 + i * 16 + rf) * 32 + kf]);
#pragma unroll
        for (int j = 0; j < 2; ++j)
            b[j] = *(const bf16x8*)(&Bs[cur][(wc * 32 + j * 16 + rf) * 32 + kf]);
#pragma unroll
        for (int i = 0; i < 2; ++i)
#pragma unroll
            for (int j = 0; j < 2; ++j)
                acc[i][j] = __builtin_amdgcn_mfma_f32_16x16x32_bf16(a[i], b[j], acc[i][j], 0, 0, 0);
        __syncthreads();
    }

    int rl = l >> 4, cl = l & 15;
#pragma unroll
    for (int i = 0; i < 2; ++i)
#pragma unroll
        for (int j = 0; j < 2; ++j)
#pragma unroll
            for (int r = 0; r < 4; ++r) {
                int row = m0 + wr * 32 + i * 16 + rl * 4 + r;
                int col = n0 + wc * 32 + j * 16 + cl;
                size_t off = (size_t)row * N + col;
                float v = acc[i][j][r];
                if (R) v += R[off];
                C[off] = v;
            }
}

// ---------------------------------------------------------------------------
// qkv GEMM + FUSED qknorm/rope/vtranspose epilogue. 1D grid 768, XCD-chunked
// swizzle (m-major logical order). ct 0-7 q-head, 8-15 k-head, 16-23 v-head.
// ---------------------------------------------------------------------------
__global__ __launch_bounds__(256) void gemm_qkv_fused_kernel(const unsigned short* __restrict__ A,
                                                             const unsigned short* __restrict__ BT,
                                                             const float* __restrict__ qs,
                                                             const float* __restrict__ cosT,
                                                             const float* __restrict__ sinT,
                                                             unsigned short* __restrict__ qh,
                                                             unsigned short* __restrict__ kh,
                                                             unsigned short* __restrict__ vt) {
    __shared__ __align__(16) unsigned char smem[128 * 65 * sizeof(float)];  // 33280B
    unsigned short* As = (unsigned short*)smem;            // [2][128*32] = 16384B
    unsigned short* Bs = (unsigned short*)(smem + 16384);  // [2][64*32]  =  8192B
    float* ex = (float*)smem;                              // [128][65] overlay
    int tid = threadIdx.x;
    // XCD-chunked bijective swizzle: 768 = 8 * 96
    int logical = (blockIdx.x % 8) * 96 + blockIdx.x / 8;
    int ct = logical % 24, m0 = (logical / 24) * 128;      // m-major
    int n0 = ct * 64;
    int w = tid >> 6, l = tid & 63;
    int wr = w >> 1, wc = w & 1;
    int kf = 8 * (l >> 4);
    int rf = l & 15;

    auto stage = [&](int buf, int k0) {
#pragma unroll
        for (int u = 0; u < 2; ++u) {
            int c = u * 256 + tid;
            int row = c >> 2, ch = c & 3;
            gload16(A + (size_t)(m0 + row) * DD + k0 + ch * 8, &As[buf * 4096 + c * 8]);
        }
        int c = tid;                            // B: 256 chunks
        int row = c >> 2, ch = c & 3;
        gload16(BT + (size_t)(n0 + row) * DD + k0 + ch * 8, &Bs[buf * 2048 + c * 8]);
    };

    f32x4 acc[4][2] = {};
    stage(0, 0);
    __syncthreads();
    for (int t = 0; t < 16; ++t) {
        if (t + 1 < 16) stage((t + 1) & 1, (t + 1) * 32);
        int cur = t & 1;
        bf16x8 a[4], b[2];
#pragma unroll
        for (int i = 0; i < 4; ++i)
            a[i] = *(const bf16x8*)(&As[cur * 4096 + (wr * 64 + i * 16 + rf) * 32 + kf]);
#pragma unroll
        for (int j = 0; j < 2; ++j)
            b[j] = *(const bf16x8*)(&Bs[cur * 2048 + (wc * 32 + j * 16 + rf) * 32 + kf]);
#pragma unroll
        for (int i = 0; i < 4; ++i)
#pragma unroll
            for (int j = 0; j < 2; ++j)
                acc[i][j] = __builtin_amdgcn_mfma_f32_16x16x32_bf16(a[i], b[j], acc[i][j], 0, 0, 0);
        __syncthreads();
    }

    // acc -> ex (staging bufs dead; barrier above fences last reads)
    int rl = l >> 4, cl = l & 15;
#pragma unroll
    for (int i = 0; i < 4; ++i)
#pragma unroll
        for (int j = 0; j < 2; ++j)
#pragma unroll
            for (int r = 0; r < 4; ++r)
                ex[(wr * 64 + i * 16 + rl * 4 + r) * 65 + wc * 32 + j * 16 + cl] = acc[i][j][r];
    __syncthreads();

    int b = m0 >> 11;            // batch (blocks never straddle: 2048 % 128 == 0)
    int lbase = m0 & (LL - 1);
    if (ct < 16) {
        int h = ct & 7;
        bool isq = ct < 8;
        float hsc = expf(0.5f * fminf(qs[h], 4.60517019f) - 1.03972077f) * 0.35355339059f;
        if (isq) hsc *= 1.44269504f;           // fold log2(e) into q for exp2 flash
        unsigned short* dst = (isq ? qh : kh) + ((size_t)(b * HH + h) * LL) * EE;
#pragma unroll 4
        for (int it = 0; it < 32; ++it) {
            int row = w * 32 + it;
            int lloc = lbase + row;
            float v = ex[row * 65 + l];        // lane = e
            float ss = v * v;
#pragma unroll
            for (int d = 1; d < 64; d <<= 1) ss += __shfl_xor(ss, d);
            float inv = hsc * rsqrtf(ss * (1.f / EE) + EPS_F);
            float pr = ex[row * 65 + (l ^ 32)];
            int i2 = l & 31;
            float c = cosT[lloc * 32 + i2], s = sinT[lloc * 32 + i2];
            float vn = v * inv, pn = pr * inv;
            float o = (l < 32) ? (vn * c - pn * s) : (pn * s + vn * c);
            dst[(size_t)lloc * EE + l] = f2bf(o);
        }
    } else {
        int h = ct - 16;
        int bh = b * HH + h;
#pragma unroll 4
        for (int it = 0; it < 16; ++it) {
            int e = w * 16 + it;
            float v0 = ex[(2 * l) * 65 + e];
            float v1 = ex[(2 * l + 1) * 65 + e];
            unsigned int pk = (unsigned int)f2bf(v0) | ((unsigned int)f2bf(v1) << 16);
            *(unsigned int*)(vt + ((size_t)(bh * EE + e)) * LL + lbase + 2 * l) = pk;
        }
    }
}

// ---------------------------------------------------------------------------
// wup GEMM + fused geglu, 2-phase dbuf staging; f32 exchange overlay.
// 1D grid 512 = 8*64, XCD-chunked (m-major: 4 m-panels x all 16 n per chunk).
// ---------------------------------------------------------------------------
__global__ __launch_bounds__(256) void gemm_geglu_kernel(const unsigned short* __restrict__ A,
                                                         const unsigned short* __restrict__ BT,
                                                         unsigned short* __restrict__ G) {
    __shared__ __align__(16) unsigned char smem[128 * 65 * sizeof(float)];  // 33280B
    unsigned short* As = (unsigned short*)smem;                 // [2][128*32]
    unsigned short* Bs = (unsigned short*)(smem + 16384);       // [2][128*32]
    float* ep = (float*)smem;                                   // [128][65] overlay
    int tid = threadIdx.x;
    int logical = (blockIdx.x % 8) * 64 + blockIdx.x / 8;       // 512 = 8*64 bijective
    int n0 = (logical % 16) * 64, m0 = (logical / 16) * 128;    // m-major
    int w = tid >> 6, l = tid & 63;
    int wr = w >> 1, wc = w & 1;
    int kf = 8 * (l >> 4);
    int rf = l & 15;

    auto stage = [&](int buf, int k0) {
#pragma unroll
        for (int u = 0; u < 2; ++u) {
            int c = u * 256 + tid;
            int row = c >> 2, ch = c & 3;
            gload16(A + (size_t)(m0 + row) * DD + k0 + ch * 8, &As[buf * 4096 + c * 8]);
            int grow = (row < 64) ? (n0 + row) : (DFF + n0 + row - 64);
            gload16(BT + (size_t)grow * DD + k0 + ch * 8, &Bs[buf * 4096 + c * 8]);
        }
    };

    f32x4 acc[4][4] = {};
    stage(0, 0);
    __syncthreads();

    for (int t = 0; t < 16; ++t) {
        if (t + 1 < 16) stage((t + 1) & 1, (t + 1) * 32);
        int cur = t & 1;
        bf16x8 a[4], b[4];
#pragma unroll
        for (int i = 0; i < 4; ++i)
            a[i] = *(const bf16x8*)(&As[cur * 4096 + (wr * 64 + i * 16 + rf) * 32 + kf]);
#pragma unroll
        for (int j = 0; j < 4; ++j)
            b[j] = *(const bf16x8*)(&Bs[cur * 4096 + (wc * 64 + j * 16 + rf) * 32 + kf]);
#pragma unroll
        for (int i = 0; i < 4; ++i)
#pragma unroll
            for (int j = 0; j < 4; ++j)
                acc[i][j] = __builtin_amdgcn_mfma_f32_16x16x32_bf16(a[i], b[j], acc[i][j], 0, 0, 0);
        __syncthreads();
    }

    int rl = l >> 4, cl = l & 15;
    if (wc == 0) {  // a-cols -> LDS (overlays dead staging buffers)
#pragma unroll
        for (int i = 0; i < 4; ++i)
#pragma unroll
            for (int j = 0; j < 4; ++j)
#pragma unroll
                for (int r = 0; r < 4; ++r)
                    ep[(wr * 64 + i * 16 + rl * 4 + r) * 65 + j * 16 + cl] = acc[i][j][r];
    }
    __syncthreads();
    if (wc == 1) {  // b-cols: g = a * gelu(b)
#pragma unroll
        for (int i = 0; i < 4; ++i)
#pragma unroll
            for (int j = 0; j < 4; ++j)
#pragma unroll
                for (int r = 0; r < 4; ++r) {
                    int row = wr * 64 + i * 16 + rl * 4 + r;
                    float bv = acc[i][j][r];
                    float av = ep[row * 65 + j * 16 + cl];
                    float ge = 0.5f * bv * (1.f + erff(bv * 0.70710678f));
                    G[(size_t)(m0 + row) * DFF + n0 + j * 16 + cl] = f2bf(av * ge);
                }
    }
}

// ---------------------------------------------------------------------------
// MFMA flash attention v11: v10 + row sums via ones-MFMA on the register
// A-fragment pa (replaces 8 adds + 2 shfls; MFMA pipe is at 14%). Same
// truncated-P in numerator AND denominator -> bias cancels exactly.
// XCD-chunked swizzle retained.
// ---------------------------------------------------------------------------
#define KVB 32
#define KLDP 72
#define VLDP 40
__global__ __launch_bounds__(256) void flash_mfma_kernel(const unsigned short* __restrict__ qh,
                                                         const unsigned short* __restrict__ kh,
                                                         const unsigned short* __restrict__ vt,
                                                         unsigned short* __restrict__ op,
                                                         float* __restrict__ os) {
    __shared__ unsigned short K_lds[2][32 * KLDP];    // [buf][kv][e]
    __shared__ unsigned short VT_lds[2][64 * VLDP];   // [buf][e][kv]
    int bid = (blockIdx.x % 8) * 256 + blockIdx.x / 8;   // XCD-chunked swizzle
    int qb = bid & 31, h = (bid >> 5) & 7, b = (bid >> 8) & 1, split = bid >> 9;
    int bh = b * HH + h;
    int tid = threadIdx.x, w = tid >> 6, l = tid & 63;
    int lo = l & 15, hi4 = l >> 4;
    int q0 = qb * 64 + w * 16;

    const unsigned short* qbase = qh + ((size_t)bh * LL) * EE;
    bf16x8 qa[2];
#pragma unroll
    for (int s = 0; s < 2; ++s)
        qa[s] = *(const bf16x8*)(qbase + (size_t)(q0 + lo) * EE + s * 32 + 8 * hi4);

    // ones B-fragment (bf16 1.0 = 0x3F80) for row-sum MFMA
    uint4 ov = make_uint4(0x3F803F80u, 0x3F803F80u, 0x3F803F80u, 0x3F803F80u);
    bf16x8 ones = *(bf16x8*)&ov;

    // per-thread staging addresses (1 K-chunk + 1 VT-chunk of 16B each)
    int krow = tid >> 3, kch = tid & 7;      // K: 32 rows x 8 chunks
    int vrow = tid >> 2, vch = tid & 3;      // VT: 64 rows x 4 chunks
    const uint4* gK = (const uint4*)(kh + ((size_t)bh * LL + split * 16 * KVB + krow) * EE + kch * 8);
    const uint4* gV = (const uint4*)(vt + ((size_t)bh * EE + vrow) * LL + split * 16 * KVB + vch * 8);
    const int gKstep = KVB * EE / 8;         // uint4 units per tile (K)
    const int gVstep = KVB / 8;              // uint4 units per tile (VT)
    unsigned short* ldsK = &K_lds[0][krow * KLDP + kch * 8];
    unsigned short* ldsV = &VT_lds[0][vrow * VLDP + vch * 8];
    const int ldsKsz = 32 * KLDP, ldsVsz = 64 * VLDP;

    uint4 pk = *gK, pv = *gV;
    *(uint4*)ldsK = pk;
    *(uint4*)ldsV = pv;
    __syncthreads();

    f32x4 oacc[4] = {};
    f32x4 osum = {};
    const bool lowg = hi4 < 2;               // g in {0,1}
    const bool oddg = hi4 & 1;
    const bool topg = hi4 >> 1;
    const int par = (hi4 ^ (hi4 >> 1)) & 1;  // 0 for g0,g3; 1 for g1,g2

    for (int t = 0; t < 16; ++t) {
        int cur = t & 1;
        if (t + 1 < 16) {                    // early issue: latency hides under compute
            pk = gK[(t + 1) * gKstep];
            pv = gV[(t + 1) * gVstep];
        }

        // S^T = K Q^T (swapped): thread holds S[kv = 16nf + 4*hi4 + r][q = lo]
        const unsigned short* Kc = &K_lds[cur][0];
        const unsigned short* Vc = &VT_lds[cur][0];
        f32x4 S[2] = {};
        __builtin_amdgcn_s_setprio(1);
#pragma unroll
        for (int nf = 0; nf < 2; ++nf)
#pragma unroll
            for (int s = 0; s < 2; ++s) {
                bf16x8 kb = *(const bf16x8*)&Kc[(nf * 16 + lo) * KLDP + s * 32 + 8 * hi4];
                S[nf] = __builtin_amdgcn_mfma_f32_16x16x32_bf16(kb, qa[s], S[nf], 0, 0, 0);
            }
        __builtin_amdgcn_s_setprio(0);

        // p = exp2(S) (log2e pre-folded into q)
        float p0 = exp2f(S[0][0]), p1 = exp2f(S[0][1]), p2 = exp2f(S[0][2]), p3 = exp2f(S[0][3]);
        float p4 = exp2f(S[1][0]), p5 = exp2f(S[1][1]), p6 = exp2f(S[1][2]), p7 = exp2f(S[1][3]);

        // pack kv-pairs: u0,u1 = pairs {2g,2g+1}; u2,u3 = {8+2g,8+2g+1}
        unsigned int u0 = packbf_t(p0, p1), u1 = packbf_t(p2, p3);
        unsigned int u2 = packbf_t(p4, p5), u3 = packbf_t(p6, p7);
        // butterfly: lane g ends with pairs {4g..4g+3} = A-fragment for q=lo
        unsigned int keep0 = lowg ? u0 : u2, keep1 = lowg ? u1 : u3;
        unsigned int sA0 = lowg ? u2 : u0, sA1 = lowg ? u3 : u1;
        unsigned int rA0 = __shfl_xor(sA0, 32), rA1 = __shfl_xor(sA1, 32);
        unsigned int sB0 = par ? keep0 : rA0, sB1 = par ? keep1 : rA1;
        unsigned int rB0 = __shfl_xor(sB0, 16), rB1 = __shfl_xor(sB1, 16);
        uint4 paw;
        paw.x = oddg ? rB0 : (topg ? rA0 : keep0);
        paw.y = oddg ? rB1 : (topg ? rA1 : keep1);
        paw.z = oddg ? (topg ? keep0 : rA0) : rB0;
        paw.w = oddg ? (topg ? keep1 : rA1) : rB1;
        bf16x8 pa = *(bf16x8*)&paw;

        // O += P V ; row sums via ones-MFMA (every output col identical)
        __builtin_amdgcn_s_setprio(1);
#pragma unroll
        for (int nf = 0; nf < 4; ++nf) {
            bf16x8 vb = *(const bf16x8*)&Vc[(nf * 16 + lo) * VLDP + 8 * hi4];
            oacc[nf] = __builtin_amdgcn_mfma_f32_16x16x32_bf16(pa, vb, oacc[nf], 0, 0, 0);
        }
        osum = __builtin_amdgcn_mfma_f32_16x16x32_bf16(pa, ones, osum, 0, 0, 0);
        __builtin_amdgcn_s_setprio(0);

        // write prefetched tile into the other buffer (its readers finished
        // before the PREVIOUS barrier), then one barrier.
        if (t + 1 < 16) {
            *(uint4*)(ldsK + (cur ^ 1) * ldsKsz) = pk;
            *(uint4*)(ldsV + (cur ^ 1) * ldsVsz) = pv;
        }
        __syncthreads();
    }

    unsigned short* opp = op + (size_t)split * (NB * LL * DD);
#pragma unroll
    for (int r = 0; r < 4; ++r) {
        int row = q0 + hi4 * 4 + r;
        unsigned short* optr = opp + ((size_t)(b * LL + row)) * DD + h * EE;
#pragma unroll
        for (int nf = 0; nf < 4; ++nf)
            optr[nf * 16 + lo] = f2bf(oacc[nf][r]);    // RNE partials
        if (lo == 0)
            os[split * (NB * HH * LL) + bh * LL + row] = osum[r];
    }
}

// ---------------------------------------------------------------------------
// combine 4 bf16 partials: oh = bf16( sum_sp op[sp] / sum_sp s[sp] )
// ---------------------------------------------------------------------------
__global__ __launch_bounds__(256) void attn_combine_kernel(const unsigned short* __restrict__ op,
                                                           const float* __restrict__ os,
                                                           unsigned short* __restrict__ oh) {
    int idx = (blockIdx.x * 256 + threadIdx.x) * 8;   // over 2M elems
    int col = idx & 511;
    int h = col >> 6;
    int row = (idx >> 9) & (LL - 1);
    int b = idx >> 20;
    int bh = b * HH + h;
    float s = 0.f;
    float a[8] = {};
#pragma unroll
    for (int sp = 0; sp < 4; ++sp) {
        s += os[sp * (NB * HH * LL) + bh * LL + row];
        uint4 t = *(const uint4*)(op + (size_t)sp * (NB * LL * DD) + idx);
        unsigned int dw[4] = {t.x, t.y, t.z, t.w};
#pragma unroll
        for (int j = 0; j < 4; ++j) {
            a[2 * j]     += __uint_as_float(dw[j] << 16);
            a[2 * j + 1] += __uint_as_float(dw[j] & 0xFFFF0000u);
        }
    }
    float inv = 1.f / s;
    uint4 o4;
    unsigned int* po = (unsigned int*)&o4;
#pragma unroll
    for (int j = 0; j < 4; ++j)
        po[j] = (unsigned int)f2bf(a[2 * j] * inv) | ((unsigned int)f2bf(a[2 * j + 1] * inv) << 16);
    *(uint4*)(oh + idx) = o4;
}

// ---------------------------------------------------------------------------
extern "C" void kernel_launch(void* const* d_in, const int* in_sizes, int n_in,
                              void* d_out, int out_size, void* d_ws, size_t ws_size,
                              hipStream_t stream) {
    const float* x        = (const float*)d_in[0];
    const float* cond     = (const float*)d_in[1];
    // d_in[2] attn_mask: bias varies only with query index -> softmax-invariant -> unused
    const float* wn_attn  = (const float*)d_in[3];
    const float* wqkv     = (const float*)d_in[4];
    const float* qk_scale = (const float*)d_in[5];
    const float* wout     = (const float*)d_in[6];
    const float* wn_ff    = (const float*)d_in[7];
    const float* wup      = (const float*)d_in[8];
    const float* wdown    = (const float*)d_in[9];
    const float* out_scale= (const float*)d_in[10];
    float* out = (float*)d_out;

    const int TOK = NB * LL;                 // 4096
    const size_t nHx = (size_t)TOK * DD;     // 2,097,152
    const size_t M = 1024 * 1024;

    float* ws = (float*)d_ws;
    float* hx  = ws;                                   // [0, 2M) f32
    unsigned short* y_bf = (unsigned short*)(ws + 2 * M);      // [2M,3M)
    unsigned short* op   = (unsigned short*)(ws + 3 * M);      // [3M,7M): 4 splits x 2M ushort
    unsigned short* qh_bf = (unsigned short*)(ws + 11 * M);    // [11M,12M)
    unsigned short* g_bf  = (unsigned short*)(ws + 11 * M);    // [11M,13M) (qh/kh dead by geglu)
    unsigned short* kh_bf = (unsigned short*)(ws + 12 * M);    // [12M,13M)
    unsigned short* vt_bf = (unsigned short*)(ws + 13 * M);    // [13M,14M)
    unsigned short* oh_bf = (unsigned short*)(ws + 14 * M);    // [14M,15M)
    unsigned short* wt = (unsigned short*)(ws + 15 * M);       // [15M,20M)
    float* smal  = ws + 20 * M;
    float* s_all = smal;                      // 8192
    float* os    = smal + 8192;               // 4 x 32768 = 131072
    float* cosT  = os + 131072;
    float* sinT  = cosT + 65536;

    hipMemcpyAsync(hx, x, nHx * sizeof(float), hipMemcpyDeviceToDevice, stream);
    rope_table_kernel<<<256, 256, 0, stream>>>(cosT, sinT);
    cond_all_kernel<<<128, 256, 0, stream>>>(cond, wn_attn, wn_ff, s_all);
    wcast_all_kernel<<<10240, 256, 0, stream>>>(wqkv, wout, wup, wdown, wt);

    unsigned short* wqkvT  = wt;
    unsigned short* woutT  = wt + 3145728;
    unsigned short* wupT   = wt + 4194304;
    unsigned short* wdownT = wt + 8388608;

    for (int layer = 0; layer < NL; ++layer) {
        const float* qs = qk_scale + layer * HH;

        rmsnorm_bf16_kernel<<<TOK, 256, 0, stream>>>(hx, s_all + (size_t)(layer * 2 + 0) * NB * DD, y_bf);
        gemm_qkv_fused_kernel<<<768, 256, 0, stream>>>(
            y_bf, wqkvT + (size_t)layer * 786432, qs, cosT, sinT, qh_bf, kh_bf, vt_bf);
        flash_mfma_kernel<<<2048, 256, 0, stream>>>(qh_bf, kh_bf, vt_bf, op, os);
        attn_combine_kernel<<<1024, 256, 0, stream>>>(op, os, oh_bf);
        gemm_bf16_64_kernel<<<512, 256, 0, stream>>>(
            oh_bf, woutT + (size_t)layer * 262144, hx, hx, TOK, 512, 512);

        rmsnorm_bf16_kernel<<<TOK, 256, 0, stream>>>(hx, s_all + (size_t)(layer * 2 + 1) * NB * DD, y_bf);
        gemm_geglu_kernel<<<512, 256, 0, stream>>>(
            y_bf, wupT + (size_t)layer * 1048576, g_bf);
        gemm_bf16_64_kernel<<<512, 256, 0, stream>>>(
            g_bf, wdownT + (size_t)layer * 524288, hx, hx, TOK, 512, 1024);
    }
    rmsnorm_f32_kernel<<<TOK, 256, 0, stream>>>(hx, out_scale, out);
}